// Round 4
// baseline (123.052 us; speedup 1.0000x reference)
//
#include <hip/hip_runtime.h>

#define NB 64
#define LC 1024
#define LQ 128
#define DD 128
#define NEG_BIG 1.0e12f

typedef __attribute__((ext_vector_type(8))) short short8;
typedef __attribute__((ext_vector_type(4))) unsigned short ushort4v;
typedef __attribute__((ext_vector_type(4))) float floatx4;

__device__ __forceinline__ float wave_reduce_max(float v) {
#pragma unroll
  for (int m = 32; m >= 1; m >>= 1) v = fmaxf(v, __shfl_xor(v, m, 64));
  return v;
}
__device__ __forceinline__ float wave_reduce_sum(float v) {
#pragma unroll
  for (int m = 32; m >= 1; m >>= 1) v += __shfl_xor(v, m, 64);
  return v;
}
__device__ __forceinline__ unsigned short f2bf(float f) {
  union { float f; unsigned int u; } v;
  v.f = f;
  const unsigned int r = v.u + 0x7FFFu + ((v.u >> 16) & 1u);
  return (unsigned short)(r >> 16);
}
__device__ __forceinline__ float bf2f(unsigned int u) {
  union { unsigned int u; float f; } v;
  v.u = u << 16;
  return v.f;
}

// ---------------------------------------------------------------------------
// K_pre_c: per (b, 64-c tile): xc -> bf16 row-major (xcb) + bf16 transposed
// (xcT[b][d][c]) + a_cont = xc . W0
// ---------------------------------------------------------------------------
__global__ __launch_bounds__(256) void k_pre_c(
    const float* __restrict__ xc, const float* __restrict__ W0,
    unsigned short* __restrict__ xcb, unsigned short* __restrict__ xcT,
    float* __restrict__ a_cont) {
  __shared__ __align__(16) unsigned short tile[64 * 136];
  const int b = blockIdx.x >> 4;
  const int c0 = (blockIdx.x & 15) << 6;
  const int t = threadIdx.x;
  const int w = t >> 6, lane = t & 63;
  const float* src = xc + ((size_t)b * LC + c0) * DD;
  unsigned short* dstb = xcb + ((size_t)b * LC + c0) * DD;

#pragma unroll
  for (int i = 0; i < 8; ++i) {
    const int id = t + (i << 8);
    const int row = id >> 5, u = id & 31;
    const float4 v = *(const float4*)(src + (size_t)row * DD + (u << 2));
    ushort4v pk;
    pk[0] = f2bf(v.x); pk[1] = f2bf(v.y); pk[2] = f2bf(v.z); pk[3] = f2bf(v.w);
    *(ushort4v*)(tile + row * 136 + (u << 2)) = pk;
    *(ushort4v*)(dstb + (size_t)row * DD + (u << 2)) = pk;
  }
  const float w0a = W0[lane << 1];
  const float w0b = W0[(lane << 1) + 1];
  __syncthreads();
#pragma unroll
  for (int r = 0; r < 16; ++r) {
    const int row = (w << 4) + r;
    const unsigned int pk = *(const unsigned int*)(tile + row * 136 + (lane << 1));
    float s = fmaf(bf2f(pk & 0xffffu), w0a, bf2f(pk >> 16) * w0b);
    s = wave_reduce_sum(s);
    if (lane == 0) a_cont[b * LC + c0 + row] = s;
  }
  // transpose write: xcT[b][d][c0+ch*32 .. +32]
  const int d = t >> 1, ch = t & 1;
  short8 o[4];
#pragma unroll
  for (int j = 0; j < 32; ++j)
    ((unsigned short*)o)[j] = tile[(ch * 32 + j) * 136 + d];
  unsigned short* dp = xcT + ((size_t)b * DD + d) * LC + c0 + ch * 32;
#pragma unroll
  for (int j = 0; j < 4; ++j) *(short8*)(dp + (j << 3)) = o[j];
}

// ---------------------------------------------------------------------------
// K_pre_q: per b: xq*W2 -> bf16 row-major (xqwb), xq -> bf16 transposed
// (xqT[b][d][q]), a_ques = xq . W1
// ---------------------------------------------------------------------------
__global__ __launch_bounds__(256) void k_pre_q(
    const float* __restrict__ xq, const float* __restrict__ W1,
    const float* __restrict__ W2, unsigned short* __restrict__ xqwb,
    unsigned short* __restrict__ xqT, float* __restrict__ a_ques) {
  __shared__ __align__(16) unsigned short tile[128 * 136];
  const int b = blockIdx.x;
  const int t = threadIdx.x;
  const int w = t >> 6, lane = t & 63;
  const float* src = xq + (size_t)b * LQ * DD;
  unsigned short* dstw = xqwb + (size_t)b * LQ * DD;

#pragma unroll
  for (int i = 0; i < 16; ++i) {
    const int id = t + (i << 8);
    const int row = id >> 5, u = id & 31;
    const float4 v = *(const float4*)(src + (size_t)row * DD + (u << 2));
    const float4 wv = *(const float4*)(W2 + (u << 2));
    ushort4v pk, pf;
    pk[0] = f2bf(v.x); pk[1] = f2bf(v.y); pk[2] = f2bf(v.z); pk[3] = f2bf(v.w);
    pf[0] = f2bf(v.x * wv.x); pf[1] = f2bf(v.y * wv.y);
    pf[2] = f2bf(v.z * wv.z); pf[3] = f2bf(v.w * wv.w);
    *(ushort4v*)(tile + row * 136 + (u << 2)) = pk;
    *(ushort4v*)(dstw + (size_t)row * DD + (u << 2)) = pf;
  }
  const float w1a = W1[lane << 1];
  const float w1b = W1[(lane << 1) + 1];
  __syncthreads();
#pragma unroll
  for (int r = 0; r < 32; ++r) {
    const int row = (w << 5) + r;
    const unsigned int pk = *(const unsigned int*)(tile + row * 136 + (lane << 1));
    float s = fmaf(bf2f(pk & 0xffffu), w1a, bf2f(pk >> 16) * w1b);
    s = wave_reduce_sum(s);
    if (lane == 0) a_ques[b * LQ + row] = s;
  }
  // transpose: xqT[b][d][q]
  const int d = t >> 1, ch = t & 1;
  short8 o[8];
#pragma unroll
  for (int j = 0; j < 64; ++j)
    ((unsigned short*)o)[j] = tile[(ch * 64 + j) * 136 + d];
  unsigned short* dp = xqT + ((size_t)b * DD + d) * LQ + ch * 64;
#pragma unroll
  for (int j = 0; j < 8; ++j) *(short8*)(dp + (j << 3)) = o[j];
}

// ---------------------------------------------------------------------------
// K1 (MFMA): S = a_cont + a_ques + (xc.W2) xq^T; q-softmax -> sbar; raw S^T -> st
// ---------------------------------------------------------------------------
#define PADW 136

__global__ __launch_bounds__(512) void k_score(
    const unsigned short* __restrict__ xcb, const unsigned short* __restrict__ xqwb,
    const float* __restrict__ a_cont, const float* __restrict__ a_ques,
    const int* __restrict__ qlen_p, float* __restrict__ out_sbar,
    float* __restrict__ out_st) {
  __shared__ __align__(16) unsigned short smem[2 * 128 * PADW];  // 69632 B
  unsigned short* xcs = smem;
  unsigned short* xqs = smem + 128 * PADW;
  float* s_tile = (float*)smem;  // [32][132] f32, aliases xcs (dead after MFMA)

  const int b = blockIdx.x >> 3;
  const int c0 = (blockIdx.x & 7) << 7;
  const int t = threadIdx.x;
  const int w = t >> 6, lane = t & 63;
  const int frow = lane & 15;
  const int kb = lane >> 4;

  const unsigned short* xcb_blk = xcb + ((size_t)b * LC + c0) * DD;
  const unsigned short* xqw_b = xqwb + (size_t)b * LQ * DD;

#pragma unroll
  for (int i = 0; i < 4; ++i) {
    const int id = t + (i << 9);
    const int row = id >> 4, u = id & 15;
    *(short8*)(xcs + row * PADW + (u << 3)) =
        *(const short8*)(xcb_blk + (size_t)row * DD + (u << 3));
    *(short8*)(xqs + row * PADW + (u << 3)) =
        *(const short8*)(xqw_b + (size_t)row * DD + (u << 3));
  }

  const int qlen = qlen_p[b];
  float ac[4], aq[8];
#pragma unroll
  for (int reg = 0; reg < 4; ++reg)
    ac[reg] = a_cont[b * LC + c0 + w * 16 + kb * 4 + reg];
#pragma unroll
  for (int n = 0; n < 8; ++n) aq[n] = a_ques[b * LQ + n * 16 + frow];

  __syncthreads();

  floatx4 acc[8];
#pragma unroll
  for (int n = 0; n < 8; ++n) acc[n] = (floatx4){0.f, 0.f, 0.f, 0.f};
  const unsigned short* arow = xcs + (w * 16 + frow) * PADW + kb * 8;
  const unsigned short* brow = xqs + frow * PADW + kb * 8;
#pragma unroll
  for (int ks = 0; ks < 4; ++ks) {
    const short8 af = *(const short8*)(arow + ks * 32);
#pragma unroll
    for (int n = 0; n < 8; ++n) {
      const short8 bf = *(const short8*)(brow + n * 16 * PADW + ks * 32);
      acc[n] = __builtin_amdgcn_mfma_f32_16x16x32_bf16(af, bf, acc[n], 0, 0, 0);
    }
  }

  float raw[8][4];
#pragma unroll
  for (int n = 0; n < 8; ++n)
#pragma unroll
    for (int reg = 0; reg < 4; ++reg) raw[n][reg] = acc[n][reg] + ac[reg] + aq[n];

  float* sbar_row0 =
      out_sbar + ((size_t)b * LC + c0 + w * 16 + kb * 4) * LQ + frow;
#pragma unroll
  for (int reg = 0; reg < 4; ++reg) {
    float x[8];
    float m = -3.4e38f;
#pragma unroll
    for (int n = 0; n < 8; ++n) {
      x[n] = raw[n][reg] - ((n * 16 + frow) < qlen ? 0.f : NEG_BIG);
      m = fmaxf(m, x[n]);
    }
#pragma unroll
    for (int msk = 8; msk >= 1; msk >>= 1) m = fmaxf(m, __shfl_xor(m, msk, 64));
    float s = 0.f;
#pragma unroll
    for (int n = 0; n < 8; ++n) {
      x[n] = __expf(x[n] - m);
      s += x[n];
    }
#pragma unroll
    for (int msk = 8; msk >= 1; msk >>= 1) s += __shfl_xor(s, msk, 64);
    const float inv = 1.0f / s;
    float* o = sbar_row0 + (size_t)reg * LQ;
#pragma unroll
    for (int n = 0; n < 8; ++n) o[n * 16] = x[n] * inv;
  }

  float* st_b = out_st + (size_t)b * LQ * LC;
#pragma unroll
  for (int p = 0; p < 4; ++p) {
    __syncthreads();
#pragma unroll
    for (int n2 = 0; n2 < 2; ++n2) {
#pragma unroll
      for (int reg = 0; reg < 4; ++reg)
        s_tile[(n2 * 16 + frow) * 132 + (w * 16 + kb * 4 + reg)] =
            raw[2 * p + n2][reg];
    }
    __syncthreads();
    const int qrow = t >> 4;
    const int cch = t & 15;
    const float4 u0 = *(const float4*)(s_tile + qrow * 132 + (cch << 2));
    const float4 u1 = *(const float4*)(s_tile + qrow * 132 + ((cch + 16) << 2));
    float* dst = st_b + (size_t)(p * 32 + qrow) * LC + c0;
    *(float4*)(dst + (cch << 2)) = u0;
    *(float4*)(dst + ((cch + 16) << 2)) = u1;
  }
}

// ---------------------------------------------------------------------------
// K_fuse: per (b, 16-q tile): masked c-softmax of raw st rows (in-register),
// write normalized st (f32), keep unnormalized P bf16 in LDS, then
// MFMA A = P @ xc (K=1024 via xcT chunks), scale by 1/s, write AbT[b][d][q] bf16.
// ---------------------------------------------------------------------------
#define PSTR 1028

__global__ __launch_bounds__(256) void k_fuse(
    float* __restrict__ st, const unsigned short* __restrict__ xcT,
    const int* __restrict__ clen_p, unsigned short* __restrict__ AbT) {
  __shared__ __align__(16) unsigned short P[16 * PSTR];  // 32896 B
  __shared__ __align__(16) unsigned short bt[128 * 72];  // 18432 B
  __shared__ unsigned short abt[128 * 20];               // 5120 B
  __shared__ float inv_s[16];

  const int b = blockIdx.x >> 3;
  const int q0 = (blockIdx.x & 7) << 4;
  const int t = threadIdx.x;
  const int w = t >> 6, lane = t & 63;
  const int frow = lane & 15, kb = lane >> 4;
  const int L = clen_p[b];
  float* st_blk = st + ((size_t)b * LQ + q0) * LC;

  // softmax: wave w owns rows w*4 .. w*4+4
#pragma unroll
  for (int r = 0; r < 4; ++r) {
    const int row = (w << 2) + r;
    float* rowp = st_blk + (size_t)row * LC;
    float4 v[4];
    float m = -3.4e38f;
#pragma unroll
    for (int ph = 0; ph < 4; ++ph) {
      const int c = (lane << 2) + (ph << 8);
      v[ph] = *(const float4*)(rowp + c);
      if (c + 0 < L) m = fmaxf(m, v[ph].x);
      if (c + 1 < L) m = fmaxf(m, v[ph].y);
      if (c + 2 < L) m = fmaxf(m, v[ph].z);
      if (c + 3 < L) m = fmaxf(m, v[ph].w);
    }
    m = wave_reduce_max(m);
    float s = 0.f;
#pragma unroll
    for (int ph = 0; ph < 4; ++ph) {
      const int c = (lane << 2) + (ph << 8);
      v[ph].x = (c + 0 < L) ? __expf(v[ph].x - m) : 0.f;
      v[ph].y = (c + 1 < L) ? __expf(v[ph].y - m) : 0.f;
      v[ph].z = (c + 2 < L) ? __expf(v[ph].z - m) : 0.f;
      v[ph].w = (c + 3 < L) ? __expf(v[ph].w - m) : 0.f;
      s += (v[ph].x + v[ph].y) + (v[ph].z + v[ph].w);
      ushort4v pk;
      pk[0] = f2bf(v[ph].x); pk[1] = f2bf(v[ph].y);
      pk[2] = f2bf(v[ph].z); pk[3] = f2bf(v[ph].w);
      *(ushort4v*)(P + row * PSTR + c) = pk;
    }
    s = wave_reduce_sum(s);
    const float inv = 1.0f / s;
    if (lane == 0) inv_s[row] = inv;
#pragma unroll
    for (int ph = 0; ph < 4; ++ph) {
      const int c = (lane << 2) + (ph << 8);
      *(float4*)(rowp + c) =
          make_float4(v[ph].x * inv, v[ph].y * inv, v[ph].z * inv, v[ph].w * inv);
    }
  }

  // GEMM: A[q][d] = sum_c P[q][c] * xc[c][d]; B-operand = xcT[d][c]
  const unsigned short* xcT_b = xcT + (size_t)b * DD * LC;
  floatx4 acc0 = (floatx4){0.f, 0.f, 0.f, 0.f};
  floatx4 acc1 = (floatx4){0.f, 0.f, 0.f, 0.f};
  for (int kc = 0; kc < 16; ++kc) {
    __syncthreads();
#pragma unroll
    for (int i = 0; i < 4; ++i) {
      const int id = t + (i << 8);
      const int row = id >> 3, u = id & 7;
      *(short8*)(bt + row * 72 + (u << 3)) =
          *(const short8*)(xcT_b + (size_t)row * LC + (kc << 6) + (u << 3));
    }
    __syncthreads();
#pragma unroll
    for (int ks = 0; ks < 2; ++ks) {
      const short8 af =
          *(const short8*)(P + frow * PSTR + (kc << 6) + ks * 32 + kb * 8);
      const short8 b0 =
          *(const short8*)(bt + ((w * 2 + 0) * 16 + frow) * 72 + ks * 32 + kb * 8);
      const short8 b1 =
          *(const short8*)(bt + ((w * 2 + 1) * 16 + frow) * 72 + ks * 32 + kb * 8);
      acc0 = __builtin_amdgcn_mfma_f32_16x16x32_bf16(af, b0, acc0, 0, 0, 0);
      acc1 = __builtin_amdgcn_mfma_f32_16x16x32_bf16(af, b1, acc1, 0, 0, 0);
    }
  }
  __syncthreads();
  const float i0 = inv_s[kb * 4 + 0], i1 = inv_s[kb * 4 + 1];
  const float i2 = inv_s[kb * 4 + 2], i3 = inv_s[kb * 4 + 3];
  {
    const int d0 = (w * 2 + 0) * 16 + frow;
    abt[d0 * 20 + kb * 4 + 0] = f2bf(acc0[0] * i0);
    abt[d0 * 20 + kb * 4 + 1] = f2bf(acc0[1] * i1);
    abt[d0 * 20 + kb * 4 + 2] = f2bf(acc0[2] * i2);
    abt[d0 * 20 + kb * 4 + 3] = f2bf(acc0[3] * i3);
    const int d1 = (w * 2 + 1) * 16 + frow;
    abt[d1 * 20 + kb * 4 + 0] = f2bf(acc1[0] * i0);
    abt[d1 * 20 + kb * 4 + 1] = f2bf(acc1[1] * i1);
    abt[d1 * 20 + kb * 4 + 2] = f2bf(acc1[2] * i2);
    abt[d1 * 20 + kb * 4 + 3] = f2bf(acc1[3] * i3);
  }
  __syncthreads();
  const int d = t >> 1, h = t & 1;
  short8 ov;
#pragma unroll
  for (int j = 0; j < 8; ++j)
    ((unsigned short*)&ov)[j] = abt[d * 20 + h * 8 + j];
  *(short8*)(AbT + ((size_t)b * DD + d) * LQ + q0 + h * 8) = ov;
}

// ---------------------------------------------------------------------------
// K_out (MFMA): c2q = Sbar@xq, q2c = Sbar@A; LDS-staged coalesced epilogue.
// block = (b, 64-c tile), 4 waves; wave owns d-range w*32 (2 n-tiles).
// out rows written as fully-contiguous 2KB float4 runs.
// ---------------------------------------------------------------------------
__global__ __launch_bounds__(256) void k_out(
    const float* __restrict__ xc, const float* __restrict__ sbar,
    const unsigned short* __restrict__ xqT, const unsigned short* __restrict__ AbT,
    float* __restrict__ out) {
  // stg[0] = c2q tile [32][132] f32, stg[1] = q2c tile; sbar bf16 staging aliases
  __shared__ __align__(16) float stg[2 * 32 * 132];  // 33792 B
  unsigned short* sbs = (unsigned short*)stg;        // 64*136 u16 = 17408 B

  const int b = blockIdx.x >> 4;
  const int c0 = (blockIdx.x & 15) << 6;
  const int t = threadIdx.x;
  const int w = t >> 6, lane = t & 63;
  const int frow = lane & 15, kb = lane >> 4;

  const float* sb_blk = sbar + ((size_t)b * LC + c0) * LQ;
#pragma unroll
  for (int i = 0; i < 8; ++i) {
    const int id = t + (i << 8);
    const int row = id >> 5, u = id & 31;
    const float4 v = *(const float4*)(sb_blk + (size_t)row * LQ + (u << 2));
    ushort4v pk;
    pk[0] = f2bf(v.x); pk[1] = f2bf(v.y); pk[2] = f2bf(v.z); pk[3] = f2bf(v.w);
    *(ushort4v*)(sbs + row * 136 + (u << 2)) = pk;
  }

  const unsigned short* xqT_b = xqT + (size_t)b * DD * LQ;
  const unsigned short* AbT_b = AbT + (size_t)b * DD * LQ;
  short8 bq[2][4], ba[2][4];
#pragma unroll
  for (int nt = 0; nt < 2; ++nt) {
    const int d = (w << 5) + (nt << 4) + frow;
#pragma unroll
    for (int ks = 0; ks < 4; ++ks) {
      bq[nt][ks] = *(const short8*)(xqT_b + (size_t)d * LQ + ks * 32 + kb * 8);
      ba[nt][ks] = *(const short8*)(AbT_b + (size_t)d * LQ + ks * 32 + kb * 8);
    }
  }
  __syncthreads();

  floatx4 accq[4][2], acca[4][2];
#pragma unroll
  for (int mt = 0; mt < 4; ++mt)
#pragma unroll
    for (int nt = 0; nt < 2; ++nt) {
      accq[mt][nt] = (floatx4){0.f, 0.f, 0.f, 0.f};
      acca[mt][nt] = (floatx4){0.f, 0.f, 0.f, 0.f};
    }
#pragma unroll
  for (int mt = 0; mt < 4; ++mt) {
#pragma unroll
    for (int ks = 0; ks < 4; ++ks) {
      const short8 af =
          *(const short8*)(sbs + ((mt << 4) + frow) * 136 + ks * 32 + kb * 8);
#pragma unroll
      for (int nt = 0; nt < 2; ++nt) {
        accq[mt][nt] =
            __builtin_amdgcn_mfma_f32_16x16x32_bf16(af, bq[nt][ks], accq[mt][nt], 0, 0, 0);
        acca[mt][nt] =
            __builtin_amdgcn_mfma_f32_16x16x32_bf16(af, ba[nt][ks], acca[mt][nt], 0, 0, 0);
      }
    }
  }

  float* out_b = out + ((size_t)b * LC + c0) * (4 * DD);
  const float* xc_blk = xc + ((size_t)b * LC + c0) * DD;

#pragma unroll
  for (int p = 0; p < 2; ++p) {
    __syncthreads();  // previous phase reads done / sbs dead
    // stage 32 c-rows of c2q, q2c into f32 LDS [c_local][d], stride 132
#pragma unroll
    for (int mh = 0; mh < 2; ++mh) {
      const int mt = 2 * p + mh;
#pragma unroll
      for (int nt = 0; nt < 2; ++nt) {
        const int d = (w << 5) + (nt << 4) + frow;
        const int cl = (mh << 4) + (kb << 2);
#pragma unroll
        for (int reg = 0; reg < 4; ++reg) {
          stg[(cl + reg) * 132 + d] = accq[mt][nt][reg];
          stg[32 * 132 + (cl + reg) * 132 + d] = acca[mt][nt][reg];
        }
      }
    }
    __syncthreads();
    // write 32 rows: wave w owns rows w*8..w*8+8; lane group g = channel
    const int g = lane >> 4;
    const int d0 = (lane & 15) << 3;
#pragma unroll
    for (int j = 0; j < 8; ++j) {
      const int rl = (w << 3) + j;          // 0..31
      const int c = (p << 5) + rl;          // 0..63
      const float4 xv0 = *(const float4*)(xc_blk + (size_t)c * DD + d0);
      const float4 xv1 = *(const float4*)(xc_blk + (size_t)c * DD + d0 + 4);
      const float4 cq0 = *(const float4*)(stg + rl * 132 + d0);
      const float4 cq1 = *(const float4*)(stg + rl * 132 + d0 + 4);
      const float4 qc0 = *(const float4*)(stg + 32 * 132 + rl * 132 + d0);
      const float4 qc1 = *(const float4*)(stg + 32 * 132 + rl * 132 + d0 + 4);
      float4 o0, o1;
      if (g == 0) { o0 = xv0; o1 = xv1; }
      else if (g == 1) { o0 = cq0; o1 = cq1; }
      else if (g == 2) {
        o0 = make_float4(xv0.x * cq0.x, xv0.y * cq0.y, xv0.z * cq0.z, xv0.w * cq0.w);
        o1 = make_float4(xv1.x * cq1.x, xv1.y * cq1.y, xv1.z * cq1.z, xv1.w * cq1.w);
      } else {
        o0 = make_float4(xv0.x * qc0.x, xv0.y * qc0.y, xv0.z * qc0.z, xv0.w * qc0.w);
        o1 = make_float4(xv1.x * qc1.x, xv1.y * qc1.y, xv1.z * qc1.z, xv1.w * qc1.w);
      }
      float* o = out_b + (size_t)c * (4 * DD) + (g << 7) + d0;
      *(float4*)(o) = o0;
      *(float4*)(o + 4) = o1;
    }
  }
}

extern "C" void kernel_launch(void* const* d_in, const int* in_sizes, int n_in,
                              void* d_out, int out_size, void* d_ws, size_t ws_size,
                              hipStream_t stream) {
  const float* xc = (const float*)d_in[0];
  const float* xq = (const float*)d_in[1];
  const float* W0 = (const float*)d_in[2];
  const float* W1 = (const float*)d_in[3];
  const float* W2 = (const float*)d_in[4];
  const int* clen = (const int*)d_in[5];
  const int* qlen = (const int*)d_in[6];

  float* out = (float*)d_out;
  float* out_sbar = out + (size_t)NB * LC * 4 * DD;
  float* out_st = out_sbar + (size_t)NB * LC * LQ;

  float* a_cont = (float*)d_ws;                       // 64K f32
  float* a_ques = a_cont + NB * LC;                   // 8K f32
  unsigned short* xcb = (unsigned short*)(a_ques + NB * LQ);  // 8.4M u16
  unsigned short* xcT = xcb + (size_t)NB * LC * DD;           // 8.4M u16
  unsigned short* xqwb = xcT + (size_t)NB * LC * DD;          // 1M u16
  unsigned short* xqT = xqwb + (size_t)NB * LQ * DD;          // 1M u16
  unsigned short* AbT = xqT + (size_t)NB * LQ * DD;           // 1M u16

  k_pre_c<<<NB * 16, 256, 0, stream>>>(xc, W0, xcb, xcT, a_cont);
  k_pre_q<<<NB, 256, 0, stream>>>(xq, W1, W2, xqwb, xqT, a_ques);
  k_score<<<NB * 8, 512, 0, stream>>>(xcb, xqwb, a_cont, a_ques, qlen,
                                      out_sbar, out_st);
  k_fuse<<<NB * 8, 256, 0, stream>>>(out_st, xcT, clen, AbT);
  k_out<<<NB * 16, 256, 0, stream>>>(xc, out_sbar, xqT, AbT, out);
}